// Round 5
// baseline (365.730 us; speedup 1.0000x reference)
//
#include <hip/hip_runtime.h>
#include <hip/hip_cooperative_groups.h>
#include <stdint.h>

namespace cg = cooperative_groups;

// BiaffineSpanHead: B=4, S=1024, IN=1024, H=256, C=8
// out[b,s,e,c] = sum_{h,g} Hs[b,s,h] U[h,c,g] He[b,e,g] + linS[b,s,c] + linE[b,e,c] + Wb[c]
//
// R5: single cooperative mega-kernel, 256 blocks x 512 threads (1 block/CU,
// 128KB dynamic LDS). Stages: prep -> K1 (Hboth) -> lin+K2 (T) -> K3 (out),
// separated by grid.sync(). K3 = proven R4 8-phase 256^2 body, 2 tiles/block.

typedef float f32x4 __attribute__((ext_vector_type(4)));
typedef __bf16 bf16x8 __attribute__((ext_vector_type(8)));
typedef unsigned int u32;
typedef unsigned short u16;
typedef const __attribute__((address_space(1))) u32* gas_ptr;
typedef __attribute__((address_space(3))) u32* las_ptr;

static __device__ __forceinline__ void load_lds16(const void* g, void* l) {
  __builtin_amdgcn_global_load_lds((gas_ptr)g, (las_ptr)l, 16, 0, 0);
}

static __device__ __forceinline__ u16 f32_to_bf16(float f) {
  union { float f; u32 u; } v; v.f = f;
  u32 r = v.u + 0x7FFFu + ((v.u >> 16) & 1u);
  return (u16)(r >> 16);
}
static __device__ __forceinline__ float bf16lo_to_f32(u32 u) {
  union { u32 u; float f; } v; v.u = u << 16;
  return v.f;
}
static __device__ __forceinline__ float bf16hi_to_f32(u32 u) {
  union { u32 u; float f; } v; v.u = u & 0xFFFF0000u;
  return v.f;
}

// stage a 64-row x 64-col bf16 stripe; LDS slot j of row r holds global
// k-group j ^ (r&7) (T2 swizzle via pre-swizzled global source, rule #21).
static __device__ __forceinline__ void stage64(u16* lds, int dst, const u16* src,
                                               int srow, int ld, int kcol, int tid) {
  const int r = tid >> 3;
  const int sl = tid & 7;
  load_lds16(src + (size_t)(srow + r) * ld + kcol + ((sl ^ (r & 7)) << 3),
             &lds[dst + tid * 8]);
}

// read an 8-elem bf16 fragment from a swizzled 64-col row
static __device__ __forceinline__ bf16x8 rd64(const u16* lds, int base, int row, int kslot) {
  return *reinterpret_cast<const bf16x8*>(&lds[base + row * 64 + ((kslot ^ (row & 7)) << 3)]);
}

// ---------------- K3 8-phase macros (R4-proven) ----------------
#define K3_LDSA(b) ((b) * 32768)
#define K3_LDSB(b) ((b) * 32768 + 16384)

#define STG_A(b, mh, t) do {                                                    \
    stage64(lds, K3_LDSA(b) + (mh) * 4096,     Ag, m0 + (mh) * 64,       256, (t) * 64, tid); \
    stage64(lds, K3_LDSA(b) + ((mh)+2) * 4096, Ag, m0 + 128 + (mh) * 64, 256, (t) * 64, tid); \
  } while (0)

#define STG_B(b, h, t) do {                                                     \
    stage64(lds, K3_LDSB(b) + (2*(h)) * 4096,   Bgz, n0 + (h) * 128,      512, (t) * 64, tid); \
    stage64(lds, K3_LDSB(b) + (2*(h)+1) * 4096, Bgz, n0 + (h) * 128 + 64, 512, (t) * 64, tid); \
  } while (0)

#define RD_A(b, mh)                                                             \
  _Pragma("unroll")                                                             \
  for (int mi = 0; mi < 4; ++mi)                                                \
  _Pragma("unroll")                                                             \
  for (int ks = 0; ks < 2; ++ks)                                                \
    aF[mi][ks] = rd64(lds, K3_LDSA(b), wr * 128 + (mh) * 64 + mi * 16 + rA, (ks << 2) | kq);

#define RD_B(b)                                                                 \
  _Pragma("unroll")                                                             \
  for (int nh = 0; nh < 2; ++nh)                                                \
  _Pragma("unroll")                                                             \
  for (int ni = 0; ni < 2; ++ni)                                                \
  _Pragma("unroll")                                                             \
  for (int ks = 0; ks < 2; ++ks)                                                \
    bF[nh][ni][ks] = rd64(lds, K3_LDSB(b), wc * 64 + nh * 32 + ni * 16 + rA, (ks << 2) | kq);

#define MFMA_Q(mh, nh)                                                          \
  __builtin_amdgcn_s_setprio(1);                                                \
  _Pragma("unroll")                                                             \
  for (int mi = 0; mi < 4; ++mi)                                                \
  _Pragma("unroll")                                                             \
  for (int ni = 0; ni < 2; ++ni)                                                \
  _Pragma("unroll")                                                             \
  for (int ks = 0; ks < 2; ++ks)                                                \
    acc[(mh)*4 + mi][(nh)*2 + ni] = __builtin_amdgcn_mfma_f32_16x16x32_bf16(    \
        aF[mi][ks], bF[nh][ni][ks], acc[(mh)*4 + mi][(nh)*2 + ni], 0, 0, 0);    \
  __builtin_amdgcn_s_setprio(0);

#define BARRIER_MID()                                                           \
  __builtin_amdgcn_sched_barrier(0);                                            \
  __builtin_amdgcn_s_barrier();                                                 \
  asm volatile("s_waitcnt lgkmcnt(0)" ::: "memory");                            \
  __builtin_amdgcn_sched_barrier(0)

#define BARRIER_END()                                                           \
  __builtin_amdgcn_sched_barrier(0);                                            \
  __builtin_amdgcn_s_barrier()

// ---------------------------------------------------------------------------
__global__ __launch_bounds__(512, 2)
void mega(const float* __restrict__ seq, const float* __restrict__ U,
          const float* __restrict__ Ww, const float* __restrict__ Wb,
          const float* __restrict__ sw, const float* __restrict__ sb,
          const float* __restrict__ ew, const float* __restrict__ eb,
          u16* __restrict__ ws, float* __restrict__ out)
{
  extern __shared__ u16 lds[];
  cg::grid_group gg = cg::this_grid();

  u16* Xbf   = ws;                      // [4096][1024]
  u16* wbf   = Xbf + 4194304;           // [512][1024]
  u16* Utbf  = wbf + 524288;            // [2048][256]
  u16* Hboth = Utbf + 524288;           // [4096][512]  (Hs | He)
  u16* Tbf   = Hboth + 2097152;         // [4096][2048]
  float* linS = (float*)(Tbf + 8388608);
  float* linE = linS + 32768;

  const int tid  = threadIdx.x;         // 0..511
  const int bid  = blockIdx.x;          // 0..255
  const int gtid = bid * 512 + tid;
  const int lane = tid & 63;
  const int wv   = tid >> 6;            // 0..7
  const int rA   = lane & 15;
  const int kq   = lane >> 4;           // 0..3

  // ======== stage P: prep (casts + U transpose) ========
  {
#pragma unroll
    for (int kk = 0; kk < 8; ++kk) {
      const int i = (gtid + kk * 131072) * 4;
      const float4 v = *reinterpret_cast<const float4*>(seq + i);
      ushort4 o;
      o.x = f32_to_bf16(v.x); o.y = f32_to_bf16(v.y);
      o.z = f32_to_bf16(v.z); o.w = f32_to_bf16(v.w);
      *reinterpret_cast<ushort4*>(Xbf + i) = o;
    }
    {
      const int i = gtid * 4;  // 0..524284
      const float* src = (i < 262144) ? (sw + i) : (ew + (i - 262144));
      const float4 v = *reinterpret_cast<const float4*>(src);
      ushort4 o;
      o.x = f32_to_bf16(v.x); o.y = f32_to_bf16(v.y);
      o.z = f32_to_bf16(v.z); o.w = f32_to_bf16(v.w);
      *reinterpret_cast<ushort4*>(wbf + i) = o;
    }
    {
      const int i = gtid * 4;          // i = n*256 + h  (n=(c,g), h)
      const int n = i >> 8;
      const int h = i & 255;
      ushort4 o;
      o.x = f32_to_bf16(U[(size_t)(h + 0) * 2048 + n]);
      o.y = f32_to_bf16(U[(size_t)(h + 1) * 2048 + n]);
      o.z = f32_to_bf16(U[(size_t)(h + 2) * 2048 + n]);
      o.w = f32_to_bf16(U[(size_t)(h + 3) * 2048 + n]);
      *reinterpret_cast<ushort4*>(Utbf + i) = o;
    }
  }
  __threadfence();
  gg.sync();

  // ======== stage 1: K1  Hboth = X @ [sw;ew]^T + bias  (4096x512x1024) ========
  {
    const int wr = wv >> 2;            // 0..1 (32-row halves)
    const int wc = wv & 3;             // 0..3 (32-col quarters)
    const int m0 = (bid >> 2) * 64;
    const int n0 = (bid & 3) * 128;
    f32x4 a1[2][2];
#pragma unroll
    for (int i = 0; i < 2; ++i)
#pragma unroll
      for (int j = 0; j < 2; ++j) a1[i][j] = (f32x4)0.f;

    for (int kt = 0; kt < 1024; kt += 64) {
      stage64(lds, 0,    Xbf, m0,      1024, kt, tid);
      stage64(lds, 4096, wbf, n0,      1024, kt, tid);
      stage64(lds, 8192, wbf, n0 + 64, 1024, kt, tid);
      __syncthreads();
      bf16x8 af[2][2], bfr[2][2];
#pragma unroll
      for (int mi = 0; mi < 2; ++mi)
#pragma unroll
        for (int ks = 0; ks < 2; ++ks)
          af[mi][ks] = rd64(lds, 0, wr * 32 + mi * 16 + rA, (ks << 2) | kq);
#pragma unroll
      for (int ni = 0; ni < 2; ++ni)
#pragma unroll
        for (int ks = 0; ks < 2; ++ks)
          bfr[ni][ks] = rd64(lds, 4096, wc * 32 + ni * 16 + rA, (ks << 2) | kq);
#pragma unroll
      for (int mi = 0; mi < 2; ++mi)
#pragma unroll
        for (int ni = 0; ni < 2; ++ni)
#pragma unroll
          for (int ks = 0; ks < 2; ++ks)
            a1[mi][ni] = __builtin_amdgcn_mfma_f32_16x16x32_bf16(
                af[mi][ks], bfr[ni][ks], a1[mi][ni], 0, 0, 0);
      __syncthreads();
    }
#pragma unroll
    for (int mi = 0; mi < 2; ++mi)
#pragma unroll
      for (int ni = 0; ni < 2; ++ni) {
        const int n = n0 + wc * 32 + ni * 16 + rA;
        const float bn = (n < 256) ? sb[n] : eb[n - 256];
        const int mr = m0 + wr * 32 + mi * 16 + kq * 4;
#pragma unroll
        for (int r = 0; r < 4; ++r)
          Hboth[(size_t)(mr + r) * 512 + n] = f32_to_bf16(a1[mi][ni][r] + bn);
      }
  }
  __threadfence();
  gg.sync();

  // ======== stage 2: lin + K2  T = Hs @ Ut^T  (4096x2048x256) ========
  if (gtid < 32768) {
    const int m = gtid >> 3;
    const int c = gtid & 7;
    const uint4* hs4 = reinterpret_cast<const uint4*>(Hboth + (size_t)m * 512);
    const uint4* he4 = reinterpret_cast<const uint4*>(Hboth + (size_t)m * 512 + 256);
    const float* wsp = Ww + c * 512;
    const float* wep = wsp + 256;
    float s1 = 0.f, s2 = 0.f;
#pragma unroll 4
    for (int t = 0; t < 32; ++t) {
      const uint4 a = hs4[t];
      const uint4 b = he4[t];
      const u32 aw[4] = {a.x, a.y, a.z, a.w};
      const u32 bw[4] = {b.x, b.y, b.z, b.w};
#pragma unroll
      for (int q = 0; q < 4; ++q) {
        const int h = t * 8 + q * 2;
        s1 += bf16lo_to_f32(aw[q]) * wsp[h] + bf16hi_to_f32(aw[q]) * wsp[h + 1];
        s2 += bf16lo_to_f32(bw[q]) * wep[h] + bf16hi_to_f32(bw[q]) * wep[h + 1];
      }
    }
    linS[gtid] = s1;
    linE[gtid] = s2 + Wb[c];
  }
  {
    const int wr = wv >> 2;            // 0..1 (64-row halves)
    const int wc = wv & 3;             // 0..3 (32-col quarters)
#pragma unroll 1
    for (int rep = 0; rep < 2; ++rep) {
      const int tile = bid + rep * 256;        // 0..511
      const int m0 = (tile >> 4) * 128;
      const int n0 = (tile & 15) * 128;
      f32x4 a2[4][2];
#pragma unroll
      for (int i = 0; i < 4; ++i)
#pragma unroll
        for (int j = 0; j < 2; ++j) a2[i][j] = (f32x4)0.f;

      for (int kt = 0; kt < 256; kt += 64) {
        stage64(lds, 0,     Hboth, m0,       512, kt, tid);   // Hs cols 0..255
        stage64(lds, 4096,  Hboth, m0 + 64,  512, kt, tid);
        stage64(lds, 8192,  Utbf,  n0,       256, kt, tid);
        stage64(lds, 12288, Utbf,  n0 + 64,  256, kt, tid);
        __syncthreads();
        bf16x8 af[4][2], bfr[2][2];
#pragma unroll
        for (int mi = 0; mi < 4; ++mi)
#pragma unroll
          for (int ks = 0; ks < 2; ++ks)
            af[mi][ks] = rd64(lds, 0, wr * 64 + mi * 16 + rA, (ks << 2) | kq);
#pragma unroll
        for (int ni = 0; ni < 2; ++ni)
#pragma unroll
          for (int ks = 0; ks < 2; ++ks)
            bfr[ni][ks] = rd64(lds, 8192, wc * 32 + ni * 16 + rA, (ks << 2) | kq);
#pragma unroll
        for (int mi = 0; mi < 4; ++mi)
#pragma unroll
          for (int ni = 0; ni < 2; ++ni)
#pragma unroll
            for (int ks = 0; ks < 2; ++ks)
              a2[mi][ni] = __builtin_amdgcn_mfma_f32_16x16x32_bf16(
                  af[mi][ks], bfr[ni][ks], a2[mi][ni], 0, 0, 0);
        __syncthreads();
      }
#pragma unroll
      for (int mi = 0; mi < 4; ++mi)
#pragma unroll
        for (int ni = 0; ni < 2; ++ni) {
          const int n = n0 + wc * 32 + ni * 16 + rA;
          const int mr = m0 + wr * 64 + mi * 16 + kq * 4;
#pragma unroll
          for (int r = 0; r < 4; ++r)
            Tbf[(size_t)(mr + r) * 2048 + n] = f32_to_bf16(a2[mi][ni][r]);
        }
    }
  }
  __threadfence();
  gg.sync();

  // ======== stage 3: K3  out[b] = T[b] @ He[b]^T + lin  (8-phase 256^2) ========
  {
    const int wr = wv >> 2;            // 0..1
    const int wc = wv & 3;             // 0..3
    f32x4 acc[8][4];
    bf16x8 aF[4][2];
    bf16x8 bF[2][2][2];
#pragma unroll 1
    for (int rep = 0; rep < 2; ++rep) {
      const int tile = bid + rep * 256;        // 0..511
      const int z = tile >> 7;
      int id = tile & 127;
      id = (id & 7) * 16 + (id >> 3);          // XCD-ish locality swizzle
      const int n0 = (id & 3) * 256;
      const int m0 = (id >> 2) * 256;

      const u16* Ag  = Tbf + (size_t)z * (8192 * 256);
      const u16* Bgz = Hboth + 256 + (size_t)z * (1024 * 512);

#pragma unroll
      for (int i = 0; i < 8; ++i)
#pragma unroll
        for (int j = 0; j < 4; ++j) acc[i][j] = (f32x4)0.f;

      // prologue: tile0 -> buf0 (full), tile1.A-mh0 -> buf1
      STG_A(0, 0, 0); STG_A(0, 1, 0); STG_B(0, 0, 0); STG_B(0, 1, 0);
      STG_A(1, 0, 1);
      asm volatile("s_waitcnt vmcnt(2)" ::: "memory");
      __builtin_amdgcn_s_barrier();

      constexpr int NT = 4;  // K=256 / BK=64
#pragma unroll
      for (int i = 0; i < NT / 2; ++i) {
        const int t1 = 2 * i + 1, t2 = 2 * i + 2, t3 = 2 * i + 3;
        // ph1
        RD_A(0, 0); RD_B(0);
        STG_A(1, 1, t1);
        BARRIER_MID();
        MFMA_Q(0, 0);
        BARRIER_END();
        // ph2
        STG_B(1, 0, t1);
        BARRIER_MID();
        MFMA_Q(0, 1);
        BARRIER_END();
        // ph3
        RD_A(0, 1);
        STG_B(1, 1, t1);
        BARRIER_MID();
        MFMA_Q(1, 1);
        BARRIER_END();
        // ph4
        if (t2 < NT) {
          STG_A(0, 0, t2);
          asm volatile("s_waitcnt vmcnt(2)" ::: "memory");
        } else {
          asm volatile("s_waitcnt vmcnt(0)" ::: "memory");
        }
        BARRIER_MID();
        MFMA_Q(1, 0);
        BARRIER_END();
        // ph5
        RD_A(1, 0); RD_B(1);
        if (t2 < NT) STG_A(0, 1, t2);
        BARRIER_MID();
        MFMA_Q(0, 0);
        BARRIER_END();
        // ph6
        if (t2 < NT) STG_B(0, 0, t2);
        BARRIER_MID();
        MFMA_Q(0, 1);
        BARRIER_END();
        // ph7
        RD_A(1, 1);
        if (t2 < NT) STG_B(0, 1, t2);
        BARRIER_MID();
        MFMA_Q(1, 1);
        BARRIER_END();
        // ph8
        if (t3 < NT) {
          STG_A(1, 0, t3);
          asm volatile("s_waitcnt vmcnt(2)" ::: "memory");
        } else {
          asm volatile("s_waitcnt vmcnt(0)" ::: "memory");
        }
        BARRIER_MID();
        MFMA_Q(1, 0);
        BARRIER_END();
      }

      // epilogue: float4 stores with lin fused
      const int rgr = kq * 4;
      float* OutZ = out + (size_t)z * 8388608;
      const float* lS = linS + (size_t)z * 8192;
      const float* lE = linE + (size_t)z * 8192;
#pragma unroll
      for (int mf = 0; mf < 8; ++mf) {
#pragma unroll
        for (int nf = 0; nf < 4; ++nf) {
          const int mBase = m0 + wr * 128 + mf * 16 + rgr;   // = s*8 + c0
          const int e = n0 + wc * 64 + (nf >> 1) * 32 + (nf & 1) * 16 + rA;
          const int s = mBase >> 3;
          const int c0 = mBase & 7;
          const float4 ls4 = *reinterpret_cast<const float4*>(lS + mBase);
          const float4 le4 = *reinterpret_cast<const float4*>(lE + (e << 3) + c0);
          float4 o;
          o.x = acc[mf][nf][0] + ls4.x + le4.x;
          o.y = acc[mf][nf][1] + ls4.y + le4.y;
          o.z = acc[mf][nf][2] + ls4.z + le4.z;
          o.w = acc[mf][nf][3] + ls4.w + le4.w;
          *reinterpret_cast<float4*>(OutZ + ((size_t)s << 13) + ((size_t)e << 3) + c0) = o;
        }
      }
      // next rep re-stages LDS only after its prologue barrier; all reads of
      // this rep's LDS completed before the final BARRIER_END above.
    }
  }
}

// ---------------------------------------------------------------------------
extern "C" void kernel_launch(void* const* d_in, const int* in_sizes, int n_in,
                              void* d_out, int out_size, void* d_ws, size_t ws_size,
                              hipStream_t stream)
{
  const float* seq = (const float*)d_in[0];
  const float* U   = (const float*)d_in[1];
  const float* Ww  = (const float*)d_in[2];
  const float* Wb  = (const float*)d_in[3];
  const float* sw  = (const float*)d_in[4];
  const float* sb  = (const float*)d_in[5];
  const float* ew  = (const float*)d_in[6];
  const float* eb  = (const float*)d_in[7];
  float* out = (float*)d_out;
  u16* ws16 = (u16*)d_ws;

  hipFuncSetAttribute(reinterpret_cast<const void*>(&mega),
                      hipFuncAttributeMaxDynamicSharedMemorySize, 131072);

  void* args[] = {(void*)&seq, (void*)&U,  (void*)&Ww, (void*)&Wb,
                  (void*)&sw,  (void*)&sb, (void*)&ew, (void*)&eb,
                  (void*)&ws16, (void*)&out};
  hipLaunchCooperativeKernel(reinterpret_cast<void*>(&mega),
                             dim3(256), dim3(512), args, 131072, stream);
}

// Round 6
// 90.295 us; speedup vs baseline: 4.0504x; 4.0504x over previous
//
#include <hip/hip_runtime.h>
#include <stdint.h>

// BiaffineSpanHead: B=4, S=1024, IN=1024, H=256, C=8
// out[b,s,e,c] = sum_{h,g} Hs[b,s,h] U[h,c,g] He[b,e,g] + linS[b,s,c] + linE[b,e,c] + Wb[c]
//
// R6: revert mega (R5 refuted co-residency). 4 launches:
//   prep -> K1 (gemm_bt) -> K2+lin (fused kernel) -> K3 (new 128^2, BK=64,
//   32KB LDS, 4 blocks/CU for write/compute overlap via TLP).

#define BDIM 256

typedef float f32x4 __attribute__((ext_vector_type(4)));
typedef __bf16 bf16x8 __attribute__((ext_vector_type(8)));
typedef unsigned int u32;
typedef unsigned short u16;
typedef const __attribute__((address_space(1))) u32* gas_ptr;
typedef __attribute__((address_space(3))) u32* las_ptr;

static __device__ __forceinline__ void load_lds16(const void* g, void* l) {
  __builtin_amdgcn_global_load_lds((gas_ptr)g, (las_ptr)l, 16, 0, 0);
}

static __device__ __forceinline__ u16 f32_to_bf16(float f) {
  union { float f; u32 u; } v; v.f = f;
  u32 r = v.u + 0x7FFFu + ((v.u >> 16) & 1u);
  return (u16)(r >> 16);
}
static __device__ __forceinline__ float bf16lo_to_f32(u32 u) {
  union { u32 u; float f; } v; v.u = u << 16;
  return v.f;
}
static __device__ __forceinline__ float bf16hi_to_f32(u32 u) {
  union { u32 u; float f; } v; v.u = u & 0xFFFF0000u;
  return v.f;
}

// stage a 32-row x 64-col bf16 stripe with 256 threads; LDS slot sl of row r
// holds global k-group sl ^ (r&7)  (T2 swizzle via pre-swizzled source).
static __device__ __forceinline__ void stage32(u16* lds, int dst, const u16* src,
                                               int srow, int ld, int kcol, int tid) {
  const int r = tid >> 3;        // 0..31
  const int sl = tid & 7;
  load_lds16(src + (size_t)(srow + r) * ld + kcol + ((sl ^ (r & 7)) << 3),
             &lds[dst + tid * 8]);
}

// read an 8-elem bf16 fragment from a swizzled 64-col row
static __device__ __forceinline__ bf16x8 rd64(const u16* lds, int base, int row, int kslot) {
  return *reinterpret_cast<const bf16x8*>(&lds[base + row * 64 + ((kslot ^ (row & 7)) << 3)]);
}

// ---------------------------------------------------------------------------
// K3: 128x128 tile, BK=64, 256 threads (4 waves 2x2), single-buffer 2-phase.
// A = T[z] [8192][256] (m=(s,c)); B = He[z] rows of Hboth (ldb=512).
// 32KB static LDS -> target 4 blocks/CU; grid (8 n, 64 m, 4 z).
// ---------------------------------------------------------------------------
__global__ __launch_bounds__(BDIM, 4)
void gemm128_biaff(const u16* __restrict__ Tall,
                   const u16* __restrict__ Bg,
                   float* __restrict__ Out,
                   const float* __restrict__ linSall,
                   const float* __restrict__ linEall)
{
  __shared__ u16 lds[2 * 8192];    // lsA at 0, lsB at 8192 (u16 units)

  const int tid  = threadIdx.x;
  const int lane = tid & 63;
  const int wv   = tid >> 6;       // 0..3
  const int wr   = wv >> 1;        // 0..1
  const int wc   = wv & 1;         // 0..1
  const int rA   = lane & 15;
  const int kq   = lane >> 4;      // 0..3
  const int z    = blockIdx.z;

  // XCD-aware bijective swizzle (nwg=512 per z, q=64)
  int id = blockIdx.y * gridDim.x + blockIdx.x;
  id = (id & 7) * 64 + (id >> 3);
  const int n0 = (id & 7) * 128;
  const int m0 = (id >> 3) * 128;

  const u16* Ag  = Tall + (size_t)z * (8192 * 256);
  const u16* Bgz = Bg   + (size_t)z * (1024 * 512);

  f32x4 acc[4][4];
#pragma unroll
  for (int i = 0; i < 4; ++i)
#pragma unroll
    for (int j = 0; j < 4; ++j) acc[i][j] = (f32x4)0.f;

#pragma unroll 1
  for (int kt = 0; kt < 256; kt += 64) {
#pragma unroll
    for (int h = 0; h < 4; ++h)
      stage32(lds, h * 2048, Ag, m0 + h * 32, 256, kt, tid);
#pragma unroll
    for (int h = 0; h < 4; ++h)
      stage32(lds, 8192 + h * 2048, Bgz, n0 + h * 32, 512, kt, tid);
    __syncthreads();

    bf16x8 aF[4][2], bF[4][2];
#pragma unroll
    for (int mi = 0; mi < 4; ++mi)
#pragma unroll
      for (int ks = 0; ks < 2; ++ks)
        aF[mi][ks] = rd64(lds, 0, wr * 64 + mi * 16 + rA, (ks << 2) | kq);
#pragma unroll
    for (int ni = 0; ni < 4; ++ni)
#pragma unroll
      for (int ks = 0; ks < 2; ++ks)
        bF[ni][ks] = rd64(lds, 8192, wc * 64 + ni * 16 + rA, (ks << 2) | kq);
#pragma unroll
    for (int mi = 0; mi < 4; ++mi)
#pragma unroll
      for (int ni = 0; ni < 4; ++ni)
#pragma unroll
        for (int ks = 0; ks < 2; ++ks)
          acc[mi][ni] = __builtin_amdgcn_mfma_f32_16x16x32_bf16(
              aF[mi][ks], bF[ni][ks], acc[mi][ni], 0, 0, 0);
    __syncthreads();
  }

  // epilogue: float4 stores with lin fused.  C/D: col=lane&15, row=kq*4+r.
  float* OutZ = Out + (size_t)z * 8388608;
  const float* lS = linSall + (size_t)z * 8192;
  const float* lE = linEall + (size_t)z * 8192;
#pragma unroll
  for (int mi = 0; mi < 4; ++mi) {
#pragma unroll
    for (int ni = 0; ni < 4; ++ni) {
      const int mBase = m0 + wr * 64 + mi * 16 + kq * 4;   // = s*8 + c0
      const int e = n0 + wc * 64 + ni * 16 + rA;
      const int s = mBase >> 3;
      const int c0 = mBase & 7;
      const float4 ls4 = *reinterpret_cast<const float4*>(lS + mBase);
      const float4 le4 = *reinterpret_cast<const float4*>(lE + (e << 3) + c0);
      float4 o;
      o.x = acc[mi][ni][0] + ls4.x + le4.x;
      o.y = acc[mi][ni][1] + ls4.y + le4.y;
      o.z = acc[mi][ni][2] + ls4.z + le4.z;
      o.w = acc[mi][ni][3] + ls4.w + le4.w;
      *reinterpret_cast<float4*>(OutZ + ((size_t)s << 13) + ((size_t)e << 3) + c0) = o;
    }
  }
}

// ---------------------------------------------------------------------------
// K1: 2-phase 128-wide B^T GEMM (R4-proven), bf16 out + dual bias.
// ---------------------------------------------------------------------------
template <int IM, int EPI>
__global__ __launch_bounds__(BDIM, 2)
void gemm_bt(const u16* __restrict__ Aall,
             const u16* __restrict__ Ball,
             void* __restrict__ OutAll,
             const int N, const int K, const int lda, const int ldb,
             const float* __restrict__ bias0,
             const float* __restrict__ bias1)
{
  constexpr int WM = IM * 16;
  constexpr int TM = 2 * WM;

  __shared__ u16 lsA[TM * 32];
  __shared__ u16 lsB[128 * 32];

  const int tid  = threadIdx.x;
  const int lane = tid & 63;
  const int wv   = tid >> 6;
  const int wr   = wv >> 1;
  const int wc   = wv & 1;

  const int gx = gridDim.x;
  const int nwg = gx * gridDim.y;
  int id = blockIdx.y * gx + blockIdx.x;
  {
    const int q = nwg >> 3;
    id = (id & 7) * q + (id >> 3);
  }
  const int n0 = (id % gx) * 128;
  const int m0 = (id / gx) * TM;

  const u16* A  = Aall;
  const u16* Bm = Ball;

  f32x4 acc[IM][4];
#pragma unroll
  for (int i = 0; i < IM; ++i)
#pragma unroll
    for (int j = 0; j < 4; ++j) acc[i][j] = (f32x4)0.f;

  const int rA = lane & 15;
  const int ko = (lane >> 4) * 8;

  for (int kt = 0; kt < K; kt += 32) {
    constexpr int CA = TM * 4;
#pragma unroll
    for (int it = 0; it < CA / BDIM; ++it) {
      const int chunk = it * BDIM + tid;
      const int row = chunk >> 2;
      const int ce = (chunk & 3) * 8;
      load_lds16(A + (size_t)(m0 + row) * lda + (kt + ce), &lsA[chunk * 8]);
    }
#pragma unroll
    for (int it = 0; it < 2; ++it) {
      const int chunk = it * BDIM + tid;
      const int row = chunk >> 2;
      const int ce = (chunk & 3) * 8;
      load_lds16(Bm + (size_t)(n0 + row) * ldb + (kt + ce), &lsB[chunk * 8]);
    }
    __syncthreads();

    bf16x8 aF[IM], bF[4];
#pragma unroll
    for (int i = 0; i < IM; ++i)
      aF[i] = *reinterpret_cast<const bf16x8*>(&lsA[(wr * WM + i * 16 + rA) * 32 + ko]);
#pragma unroll
    for (int j = 0; j < 4; ++j)
      bF[j] = *reinterpret_cast<const bf16x8*>(&lsB[(wc * 64 + j * 16 + rA) * 32 + ko]);
#pragma unroll
    for (int i = 0; i < IM; ++i)
#pragma unroll
      for (int j = 0; j < 4; ++j)
        acc[i][j] = __builtin_amdgcn_mfma_f32_16x16x32_bf16(aF[i], bF[j], acc[i][j], 0, 0, 0);
    __syncthreads();
  }

  const int rgr = (lane >> 4) * 4;
  u16* Out = (u16*)OutAll;
#pragma unroll
  for (int i = 0; i < IM; ++i) {
#pragma unroll
    for (int j = 0; j < 4; ++j) {
      const int mBase = m0 + wr * WM + i * 16 + rgr;
      const int n = n0 + wc * 64 + j * 16 + rA;
      float bn = 0.f;
      if constexpr (EPI == 1) bn = (n < 256) ? bias0[n] : bias1[n - 256];
#pragma unroll
      for (int r = 0; r < 4; ++r) {
        Out[(size_t)(mBase + r) * N + n] = f32_to_bf16(acc[i][j][r] + bn);
      }
    }
  }
}

// ---------------------------------------------------------------------------
// K2 + lin fused: blocks 0..511 = K2 tiles (T = Hs @ Ut^T, 128^2, BK=32);
// blocks 512..639 = lin (linS/linE).
// ---------------------------------------------------------------------------
__global__ __launch_bounds__(BDIM, 2)
void k2lin(const u16* __restrict__ Hboth,
           const u16* __restrict__ Utbf,
           u16* __restrict__ Tbf,
           const float* __restrict__ Ww,
           const float* __restrict__ Wb,
           float* __restrict__ linS,
           float* __restrict__ linE)
{
  const int bid = blockIdx.x;
  const int tid = threadIdx.x;

  if (bid >= 512) {
    // ---- lin branch ----
    const int idx = (bid - 512) * BDIM + tid;   // 0..32767
    const int m = idx >> 3;
    const int c = idx & 7;
    const uint4* hs4 = reinterpret_cast<const uint4*>(Hboth + (size_t)m * 512);
    const uint4* he4 = reinterpret_cast<const uint4*>(Hboth + (size_t)m * 512 + 256);
    const float* wsp = Ww + c * 512;
    const float* wep = wsp + 256;
    float s1 = 0.f, s2 = 0.f;
#pragma unroll 4
    for (int t = 0; t < 32; ++t) {
      const uint4 a = hs4[t];
      const uint4 b = he4[t];
      const u32 aw[4] = {a.x, a.y, a.z, a.w};
      const u32 bw[4] = {b.x, b.y, b.z, b.w};
#pragma unroll
      for (int q = 0; q < 4; ++q) {
        const int h = t * 8 + q * 2;
        s1 += bf16lo_to_f32(aw[q]) * wsp[h] + bf16hi_to_f32(aw[q]) * wsp[h + 1];
        s2 += bf16lo_to_f32(bw[q]) * wep[h] + bf16hi_to_f32(bw[q]) * wep[h + 1];
      }
    }
    linS[idx] = s1;
    linE[idx] = s2 + Wb[c];
    return;
  }

  // ---- K2 branch: tile id over 512 (16 n x 32 m), XCD swizzle q=64 ----
  __shared__ u16 lsA[128 * 32];
  __shared__ u16 lsB[128 * 32];

  int id = bid;
  id = (id & 7) * 64 + (id >> 3);
  const int n0 = (id & 15) * 128;
  const int m0 = (id >> 4) * 128;

  const int lane = tid & 63;
  const int wv   = tid >> 6;
  const int wr   = wv >> 1;
  const int wc   = wv & 1;
  const int rA   = lane & 15;
  const int ko   = (lane >> 4) * 8;

  f32x4 acc[4][4];
#pragma unroll
  for (int i = 0; i < 4; ++i)
#pragma unroll
    for (int j = 0; j < 4; ++j) acc[i][j] = (f32x4)0.f;

  for (int kt = 0; kt < 256; kt += 32) {
#pragma unroll
    for (int it = 0; it < 2; ++it) {
      const int chunk = it * BDIM + tid;
      const int row = chunk >> 2;
      const int ce = (chunk & 3) * 8;
      load_lds16(Hboth + (size_t)(m0 + row) * 512 + (kt + ce), &lsA[chunk * 8]);
      load_lds16(Utbf + (size_t)(n0 + row) * 256 + (kt + ce), &lsB[chunk * 8]);
    }
    __syncthreads();

    bf16x8 aF[4], bF[4];
#pragma unroll
    for (int i = 0; i < 4; ++i)
      aF[i] = *reinterpret_cast<const bf16x8*>(&lsA[(wr * 64 + i * 16 + rA) * 32 + ko]);
#pragma unroll
    for (int j = 0; j < 4; ++j)
      bF[j] = *reinterpret_cast<const bf16x8*>(&lsB[(wc * 64 + j * 16 + rA) * 32 + ko]);
#pragma unroll
    for (int i = 0; i < 4; ++i)
#pragma unroll
      for (int j = 0; j < 4; ++j)
        acc[i][j] = __builtin_amdgcn_mfma_f32_16x16x32_bf16(aF[i], bF[j], acc[i][j], 0, 0, 0);
    __syncthreads();
  }

  const int rgr = (lane >> 4) * 4;
#pragma unroll
  for (int i = 0; i < 4; ++i) {
#pragma unroll
    for (int j = 0; j < 4; ++j) {
      const int mBase = m0 + wr * 64 + i * 16 + rgr;
      const int n = n0 + wc * 64 + j * 16 + rA;
#pragma unroll
      for (int r = 0; r < 4; ++r)
        Tbf[(size_t)(mBase + r) * 2048 + n] = f32_to_bf16(acc[i][j][r]);
    }
  }
}

// ---------------------------------------------------------------------------
__global__ void prep_kernel(const float* __restrict__ seq,
                            const float* __restrict__ sw,
                            const float* __restrict__ ew,
                            const float* __restrict__ U,
                            u16* __restrict__ Xbf,
                            u16* __restrict__ wbf,
                            u16* __restrict__ Ut)
{
  const int bid = blockIdx.x;
  const int tid = threadIdx.x;
  if (bid < 4096) {
    const int i = bid * 1024 + tid * 4;
    const float4 v = *reinterpret_cast<const float4*>(seq + i);
    ushort4 o;
    o.x = f32_to_bf16(v.x); o.y = f32_to_bf16(v.y);
    o.z = f32_to_bf16(v.z); o.w = f32_to_bf16(v.w);
    *reinterpret_cast<ushort4*>(Xbf + i) = o;
  } else if (bid < 4608) {
    const int i = (bid - 4096) * 1024 + tid * 4;
    const float* src = (i < 262144) ? (sw + i) : (ew + (i - 262144));
    const float4 v = *reinterpret_cast<const float4*>(src);
    ushort4 o;
    o.x = f32_to_bf16(v.x); o.y = f32_to_bf16(v.y);
    o.z = f32_to_bf16(v.z); o.w = f32_to_bf16(v.w);
    *reinterpret_cast<ushort4*>(wbf + i) = o;
  } else {
    const int i = (bid - 4608) * 1024 + tid * 4;  // i = n*256 + h
    const int n = i >> 8;
    const int h = i & 255;
    ushort4 o;
    o.x = f32_to_bf16(U[(size_t)(h + 0) * 2048 + n]);
    o.y = f32_to_bf16(U[(size_t)(h + 1) * 2048 + n]);
    o.z = f32_to_bf16(U[(size_t)(h + 2) * 2048 + n]);
    o.w = f32_to_bf16(U[(size_t)(h + 3) * 2048 + n]);
    *reinterpret_cast<ushort4*>(Ut + i) = o;
  }
}

// ---------------------------------------------------------------------------
extern "C" void kernel_launch(void* const* d_in, const int* in_sizes, int n_in,
                              void* d_out, int out_size, void* d_ws, size_t ws_size,
                              hipStream_t stream)
{
  const float* seq = (const float*)d_in[0];
  const float* U   = (const float*)d_in[1];
  const float* Ww  = (const float*)d_in[2];
  const float* Wb  = (const float*)d_in[3];
  const float* sw  = (const float*)d_in[4];
  const float* sb  = (const float*)d_in[5];
  const float* ew  = (const float*)d_in[6];
  const float* eb  = (const float*)d_in[7];
  float* out = (float*)d_out;

  u16* Xbf   = (u16*)d_ws;                 // 4194304
  u16* wbf   = Xbf  + 4194304;             // 524288  [512][1024]
  u16* Utbf  = wbf  + 524288;              // 524288  [2048][256]
  u16* Hboth = Utbf + 524288;              // 2097152 [4096][512]
  u16* Tbf   = Hboth + 2097152;            // 8388608 [4096][2048]
  float* linS = (float*)(Tbf + 8388608);   // 32768
  float* linE = linS + 32768;              // 32768

  prep_kernel<<<5120, BDIM, 0, stream>>>(seq, sw, ew, U, Xbf, wbf, Utbf);

  // K1: Hboth = X @ [sw;ew]^T + [sb;eb]  (M=4096, N=512, K=1024)
  gemm_bt<2, 1><<<dim3(4, 64, 1), BDIM, 0, stream>>>(
      Xbf, wbf, Hboth, 512, 1024, 1024, 1024, sb, eb);

  // K2 (T = Hs @ Ut^T) + lin, fused into one launch
  k2lin<<<640, BDIM, 0, stream>>>(Hboth, Utbf, Tbf, Ww, Wb, linS, linE);

  // K3: out[b] = T[b] @ He[b]^T + lin  (128^2, BK=64, 4 blocks/CU)
  gemm128_biaff<<<dim3(8, 64, 4), BDIM, 0, stream>>>(
      Tbf, Hboth + 256, out, linS, linE);
}